// Round 3
// baseline (234.386 us; speedup 1.0000x reference)
//
#include <hip/hip_runtime.h>
#include <math.h>

#define Bv 32
#define Cv 256
#define Hv 32
#define Wv 32
#define Pv 1024                  // H*W
#define TSTRIDE (Bv * Cv * Pv)   // elements between T-slabs = 8388608
#define NCH 16                   // channel chunks
#define CC  (Cv / NCH)           // channels per chunk = 16

// Fused kernel: grid (NCH, B), 256 threads/block.
// Phase 1: each block reduces its 16 channels' T-mean into per-pixel partials
//          (sum, sumsq). Thread t owns pixels [4t,4t+4) via float4 — fully
//          coalesced 1 KiB/wave/instruction.
// Arrival: device-scope fence + atomicAdd on cnt[b]; the 16th arriver for
//          batch b runs Phase 2 (no grid barrier, no co-residency assumption).
// Phase 2: reduce 16 chunk-partials (128 KB, L2-hot), 3x3 zero-padded box sum
//          via 34x34 haloed LDS tile, cosine sim, mask, shuffle softmax.
__global__ __launch_bounds__(256) void lss_fused(
    const float* __restrict__ x,
    const int*   __restrict__ mask,
    float*       __restrict__ out,
    float*       __restrict__ part1,
    float*       __restrict__ part2,
    int*         __restrict__ cnt)
{
    const int chunk = blockIdx.x;
    const int b     = blockIdx.y;
    const int tid   = threadIdx.x;
    const int p4    = tid << 2;

    // ---------------- Phase 1: channel-chunk partial reduction ----------------
    {
        float s1x = 0.f, s1y = 0.f, s1z = 0.f, s1w = 0.f;
        float s2x = 0.f, s2y = 0.f, s2z = 0.f, s2w = 0.f;

        const float* bp = x + ((size_t)b * Cv + chunk * CC) * Pv + p4;

        #pragma unroll 4
        for (int c = 0; c < CC; ++c) {
            const float4 v0 = *(const float4*)(bp);
            const float4 v1 = *(const float4*)(bp + (size_t)TSTRIDE);
            const float4 v2 = *(const float4*)(bp + (size_t)2 * TSTRIDE);
            const float4 v3 = *(const float4*)(bp + (size_t)3 * TSTRIDE);
            bp += Pv;

            const float mx = (v0.x + v1.x + v2.x + v3.x) * 0.25f;
            const float my = (v0.y + v1.y + v2.y + v3.y) * 0.25f;
            const float mz = (v0.z + v1.z + v2.z + v3.z) * 0.25f;
            const float mw = (v0.w + v1.w + v2.w + v3.w) * 0.25f;

            s1x += mx;  s2x += mx * mx;
            s1y += my;  s2y += my * my;
            s1z += mz;  s2z += mz * mz;
            s1w += mw;  s2w += mw * mw;
        }

        const size_t o = ((size_t)chunk * Bv + b) * Pv + p4;
        float4 r1; r1.x = s1x; r1.y = s1y; r1.z = s1z; r1.w = s1w;
        float4 r2; r2.x = s2x; r2.y = s2y; r2.z = s2z; r2.w = s2w;
        *(float4*)(part1 + o) = r1;
        *(float4*)(part2 + o) = r2;
    }

    // ---------------- Arrival: last block for batch b finalizes ----------------
    __shared__ int s_last;
    if (tid == 0) {
        __threadfence();                         // release partials (device scope)
        s_last = (atomicAdd(&cnt[b], 1) == NCH - 1);
    }
    __syncthreads();
    if (!s_last) return;
    __threadfence();                             // acquire other blocks' partials

    // ---------------- Phase 2: finalize batch b ----------------
    __shared__ float cs[(Hv + 2) * (Wv + 2)];    // zero-haloed csum tile
    __shared__ float wred[4];

    float c0 = 0.f, c1 = 0.f, c2 = 0.f, c3 = 0.f;   // csum for 4 pixels
    float q0 = 0.f, q1 = 0.f, q2 = 0.f, q3 = 0.f;   // sumsq for 4 pixels
    #pragma unroll
    for (int ch = 0; ch < NCH; ++ch) {
        const size_t o = ((size_t)ch * Bv + b) * Pv + p4;
        const float4 a = *(const float4*)(part1 + o);
        const float4 s = *(const float4*)(part2 + o);
        c0 += a.x; c1 += a.y; c2 += a.z; c3 += a.w;
        q0 += s.x; q1 += s.y; q2 += s.z; q3 += s.w;
    }
    const float nx0 = sqrtf(q0), nx1 = sqrtf(q1), nx2 = sqrtf(q2), nx3 = sqrtf(q3);

    // Build haloed csum tile.
    for (int i = tid; i < (Hv + 2) * (Wv + 2); i += 256) cs[i] = 0.f;
    __syncthreads();
    const int yy  = tid >> 3;          // row 0..31 (8 threads/row, 4 px each)
    const int xx0 = (tid & 7) << 2;    // col of first pixel
    float* crow = &cs[(yy + 1) * (Wv + 2) + (xx0 + 1)];
    crow[0] = c0; crow[1] = c1; crow[2] = c2; crow[3] = c3;
    __syncthreads();

    // 3x3 box sum / 9 for 4 consecutive pixels: read 6 floats per row.
    float lm0 = 0.f, lm1 = 0.f, lm2 = 0.f, lm3 = 0.f;
    #pragma unroll
    for (int dy = 0; dy < 3; ++dy) {
        const float* r = &cs[(yy + dy) * (Wv + 2) + xx0];
        const float r0 = r[0], r1 = r[1], r2 = r[2], r3 = r[3], r4 = r[4], r5 = r[5];
        lm0 += r0 + r1 + r2;
        lm1 += r1 + r2 + r3;
        lm2 += r2 + r3 + r4;
        lm3 += r3 + r4 + r5;
    }
    lm0 *= (1.0f / 9.0f); lm1 *= (1.0f / 9.0f);
    lm2 *= (1.0f / 9.0f); lm3 *= (1.0f / 9.0f);

    // cosine sim; ny = sqrt(256)*|lm| = 16*|lm|
    const float sim0 = (lm0 * c0) / (fmaxf(nx0, 1e-6f) * fmaxf(16.0f * fabsf(lm0), 1e-6f));
    const float sim1 = (lm1 * c1) / (fmaxf(nx1, 1e-6f) * fmaxf(16.0f * fabsf(lm1), 1e-6f));
    const float sim2 = (lm2 * c2) / (fmaxf(nx2, 1e-6f) * fmaxf(16.0f * fabsf(lm2), 1e-6f));
    const float sim3 = (lm3 * c3) / (fmaxf(nx3, 1e-6f) * fmaxf(16.0f * fabsf(lm3), 1e-6f));

    const int4 mk = *(const int4*)(mask + b * Pv + p4);
    float sc0 = mk.x ? -INFINITY : -sim0;
    float sc1 = mk.y ? -INFINITY : -sim1;
    float sc2 = mk.z ? -INFINITY : -sim2;
    float sc3 = mk.w ? -INFINITY : -sim3;

    // --- softmax over the 1024 pixels: 4-local + wave shuffle + 4-wave LDS ---
    const int wid = tid >> 6;
    float v = fmaxf(fmaxf(sc0, sc1), fmaxf(sc2, sc3));
    #pragma unroll
    for (int off = 32; off > 0; off >>= 1)
        v = fmaxf(v, __shfl_xor(v, off, 64));
    if ((tid & 63) == 0) wred[wid] = v;
    __syncthreads();
    const float m = fmaxf(fmaxf(wred[0], wred[1]), fmaxf(wred[2], wred[3]));
    __syncthreads();

    const float e0 = expf(sc0 - m), e1 = expf(sc1 - m);
    const float e2 = expf(sc2 - m), e3 = expf(sc3 - m);

    v = (e0 + e1) + (e2 + e3);
    #pragma unroll
    for (int off = 32; off > 0; off >>= 1)
        v += __shfl_xor(v, off, 64);
    if ((tid & 63) == 0) wred[wid] = v;
    __syncthreads();
    const float inv = 1.0f / (((wred[0] + wred[1]) + (wred[2] + wred[3])));

    float4 r; r.x = e0 * inv; r.y = e1 * inv; r.z = e2 * inv; r.w = e3 * inv;
    *(float4*)(out + b * Pv + p4) = r;
}

extern "C" void kernel_launch(void* const* d_in, const int* in_sizes, int n_in,
                              void* d_out, int out_size, void* d_ws, size_t ws_size,
                              hipStream_t stream) {
    const float* x    = (const float*)d_in[0];
    const int*   mask = (const int*)d_in[1];
    float*       out  = (float*)d_out;

    float* part1 = (float*)d_ws;                          // NCH*B*P floats = 2 MB
    float* part2 = part1 + (size_t)NCH * Bv * Pv;         // 2 MB
    int*   cnt   = (int*)(part2 + (size_t)NCH * Bv * Pv); // B ints

    // Zero the arrival counters (ws is poisoned 0xAA before every launch).
    hipMemsetAsync(cnt, 0, Bv * sizeof(int), stream);

    dim3 grid(NCH, Bv);
    lss_fused<<<grid, 256, 0, stream>>>(x, mask, out, part1, part2, cnt);
}

// Round 4
// 192.404 us; speedup vs baseline: 1.2182x; 1.2182x over previous
//
#include <hip/hip_runtime.h>
#include <math.h>

#define Bv 32
#define Cv 256
#define Hv 32
#define Wv 32
#define Pv 1024                  // H*W
#define TSTRIDE (Bv * Cv * Pv)   // elements between T-slabs = 8388608
#define NCH 16                   // channel chunks
#define CC  16                   // channels per chunk
#define PSPLIT 4                 // pixel quarters per (chunk,b)

// ---------------------------------------------------------------------------
// Phase 1: grid (NCH*PSPLIT, B) = 2048 blocks, 256 threads.
// Block covers: 16 channels x 256 pixels (quarter of a row-space), all 4 T.
// Thread layout: cl = tid>>6 picks one of 4 channel sub-rows, lane = tid&63
// picks a float4 within the 256-pixel span -> each wave reads a contiguous
// 1 KiB run; 16 fully-unrolled loads/thread give a deep vmcnt pipeline.
// Cross-cl combine via a small LDS tile. No fences, no atomics.
// ---------------------------------------------------------------------------
__global__ __launch_bounds__(256) void lss_phase1(
    const float* __restrict__ x,
    float* __restrict__ part1,
    float* __restrict__ part2)
{
    const int chunk = blockIdx.x >> 2;       // 0..15
    const int ps    = blockIdx.x & 3;        // 0..3 pixel quarter
    const int b     = blockIdx.y;
    const int tid   = threadIdx.x;
    const int cl    = tid >> 6;              // 0..3 channel sub-row
    const int lane  = tid & 63;
    const int p0    = ps * 256 + (lane << 2);

    float s1x = 0.f, s1y = 0.f, s1z = 0.f, s1w = 0.f;
    float s2x = 0.f, s2y = 0.f, s2z = 0.f, s2w = 0.f;

    const float* bp = x + ((size_t)b * Cv + chunk * CC + cl) * Pv + p0;

    #pragma unroll
    for (int g = 0; g < CC / 4; ++g) {       // c = chunk*16 + cl + 4*g
        const float4 v0 = *(const float4*)(bp);
        const float4 v1 = *(const float4*)(bp + (size_t)TSTRIDE);
        const float4 v2 = *(const float4*)(bp + (size_t)2 * TSTRIDE);
        const float4 v3 = *(const float4*)(bp + (size_t)3 * TSTRIDE);
        bp += 4 * Pv;

        const float mx = (v0.x + v1.x + v2.x + v3.x) * 0.25f;
        const float my = (v0.y + v1.y + v2.y + v3.y) * 0.25f;
        const float mz = (v0.z + v1.z + v2.z + v3.z) * 0.25f;
        const float mw = (v0.w + v1.w + v2.w + v3.w) * 0.25f;

        s1x += mx;  s2x += mx * mx;
        s1y += my;  s2y += my * my;
        s1z += mz;  s2z += mz * mz;
        s1w += mw;  s2w += mw * mw;
    }

    // Combine the 4 channel sub-rows (same pixels) via LDS.
    __shared__ float4 l1[4][64];
    __shared__ float4 l2[4][64];
    l1[cl][lane].x = s1x; l1[cl][lane].y = s1y; l1[cl][lane].z = s1z; l1[cl][lane].w = s1w;
    l2[cl][lane].x = s2x; l2[cl][lane].y = s2y; l2[cl][lane].z = s2z; l2[cl][lane].w = s2w;
    __syncthreads();

    if (tid < 128) {
        const int t = tid & 63;
        const float4* src = (tid < 64) ? &l1[0][0] : &l2[0][0];
        const float4 a = src[t], c = src[64 + t], d = src[128 + t], e = src[192 + t];
        float4 r;
        r.x = (a.x + c.x) + (d.x + e.x);
        r.y = (a.y + c.y) + (d.y + e.y);
        r.z = (a.z + c.z) + (d.z + e.z);
        r.w = (a.w + c.w) + (d.w + e.w);
        float* dst = (tid < 64) ? part1 : part2;
        *(float4*)(dst + ((size_t)chunk * Bv + b) * Pv + ps * 256 + (t << 2)) = r;
    }
}

// ---------------------------------------------------------------------------
// Phase 2: one block per batch, 1024 threads (1 pixel each). Reduce the 16
// chunk partials (4 MB total, L2/L3-hot), 3x3 zero-padded box sum via haloed
// LDS tile, cosine sim, mask, shuffle-based softmax (4 barriers).
// ---------------------------------------------------------------------------
__global__ __launch_bounds__(1024) void lss_final(
    const float* __restrict__ part1,
    const float* __restrict__ part2,
    const int*   __restrict__ mask,
    float*       __restrict__ out)
{
    const int b   = blockIdx.x;
    const int tid = threadIdx.x;           // p in [0, 1024)
    const int yy  = tid >> 5;
    const int xx  = tid & 31;
    const int wid = tid >> 6;              // 16 waves

    __shared__ float cs[(Hv + 2) * (Wv + 2)];
    __shared__ float wred[16];

    float s1 = 0.f, s2 = 0.f;
    #pragma unroll
    for (int ch = 0; ch < NCH; ++ch) {
        const size_t o = ((size_t)ch * Bv + b) * Pv + tid;
        s1 += part1[o];
        s2 += part2[o];
    }
    const float csum = s1;
    const float nx   = sqrtf(s2);

    for (int i = tid; i < (Hv + 2) * (Wv + 2); i += Pv) cs[i] = 0.f;
    __syncthreads();
    cs[(yy + 1) * (Wv + 2) + (xx + 1)] = csum;
    __syncthreads();

    float lm = 0.f;
    #pragma unroll
    for (int dy = 0; dy < 3; ++dy)
        #pragma unroll
        for (int dx = 0; dx < 3; ++dx)
            lm += cs[(yy + dy) * (Wv + 2) + (xx + dx)];
    lm *= (1.0f / 9.0f);

    // cosine sim: dot = lm*csum ; ny = sqrt(256)*|lm| = 16*|lm|
    const float ny  = 16.0f * fabsf(lm);
    const float sim = (lm * csum) / (fmaxf(nx, 1e-6f) * fmaxf(ny, 1e-6f));

    const float score = mask[b * Pv + tid] ? -INFINITY : -sim;

    // max reduce: wave shuffle + 16-entry LDS combine
    float v = score;
    #pragma unroll
    for (int off = 32; off > 0; off >>= 1)
        v = fmaxf(v, __shfl_xor(v, off, 64));
    if ((tid & 63) == 0) wred[wid] = v;
    __syncthreads();
    float m = wred[0];
    #pragma unroll
    for (int i = 1; i < 16; ++i) m = fmaxf(m, wred[i]);
    __syncthreads();

    const float e = expf(score - m);       // masked lanes -> 0

    // sum reduce
    v = e;
    #pragma unroll
    for (int off = 32; off > 0; off >>= 1)
        v += __shfl_xor(v, off, 64);
    if ((tid & 63) == 0) wred[wid] = v;
    __syncthreads();
    float denom = 0.f;
    #pragma unroll
    for (int i = 0; i < 16; ++i) denom += wred[i];

    out[b * Pv + tid] = e / denom;
}

extern "C" void kernel_launch(void* const* d_in, const int* in_sizes, int n_in,
                              void* d_out, int out_size, void* d_ws, size_t ws_size,
                              hipStream_t stream) {
    const float* x    = (const float*)d_in[0];
    const int*   mask = (const int*)d_in[1];
    float*       out  = (float*)d_out;

    float* part1 = (float*)d_ws;                      // NCH*B*P floats = 2 MB
    float* part2 = part1 + (size_t)NCH * Bv * Pv;     // 2 MB

    dim3 g1(NCH * PSPLIT, Bv);
    lss_phase1<<<g1, 256, 0, stream>>>(x, part1, part2);
    lss_final<<<Bv, Pv, 0, stream>>>(part1, part2, mask, out);
}

// Round 6
// 192.331 us; speedup vs baseline: 1.2187x; 1.0004x over previous
//
#include <hip/hip_runtime.h>
#include <math.h>

#define Bv 32
#define Cv 256
#define Hv 32
#define Wv 32
#define Pv 1024                  // H*W
#define TSTRIDE (Bv * Cv * Pv)   // elements between T-slabs = 8388608
#define NCH 16                   // channel chunks
#define CC  16                   // channels per chunk
#define PSPLIT 4                 // pixel quarters per (chunk,b)

// ---------------------------------------------------------------------------
// Phase 1 (R4-proven, absmax 0.0, ~87% of achievable HBM BW):
// grid (NCH*PSPLIT, B) = 2048 blocks (8/CU, 32 waves/CU), 256 threads.
// Block: 16 channels x 256 pixels x 4 T. cl = tid>>6 picks a channel sub-row,
// lane picks a float4 -> each wave reads contiguous 1 KiB; 16 unrolled loads
// per thread keep a deep vmcnt pipeline. LDS combine across the 4 sub-rows.
// No fences, no atomics (R3 showed device-scope arrival costs ~50 us).
// ---------------------------------------------------------------------------
__global__ __launch_bounds__(256) void lss_phase1(
    const float* __restrict__ x,
    float* __restrict__ part1,
    float* __restrict__ part2)
{
    const int chunk = blockIdx.x >> 2;       // 0..15
    const int ps    = blockIdx.x & 3;        // 0..3 pixel quarter
    const int b     = blockIdx.y;
    const int tid   = threadIdx.x;
    const int cl    = tid >> 6;              // 0..3 channel sub-row
    const int lane  = tid & 63;
    const int p0    = ps * 256 + (lane << 2);

    float s1x = 0.f, s1y = 0.f, s1z = 0.f, s1w = 0.f;
    float s2x = 0.f, s2y = 0.f, s2z = 0.f, s2w = 0.f;

    const float* bp = x + ((size_t)b * Cv + chunk * CC + cl) * Pv + p0;

    #pragma unroll
    for (int g = 0; g < CC / 4; ++g) {       // c = chunk*16 + cl + 4*g
        const float4 v0 = *(const float4*)(bp);
        const float4 v1 = *(const float4*)(bp + (size_t)TSTRIDE);
        const float4 v2 = *(const float4*)(bp + (size_t)2 * TSTRIDE);
        const float4 v3 = *(const float4*)(bp + (size_t)3 * TSTRIDE);
        bp += 4 * Pv;

        const float mx = (v0.x + v1.x + v2.x + v3.x) * 0.25f;
        const float my = (v0.y + v1.y + v2.y + v3.y) * 0.25f;
        const float mz = (v0.z + v1.z + v2.z + v3.z) * 0.25f;
        const float mw = (v0.w + v1.w + v2.w + v3.w) * 0.25f;

        s1x += mx;  s2x += mx * mx;
        s1y += my;  s2y += my * my;
        s1z += mz;  s2z += mz * mz;
        s1w += mw;  s2w += mw * mw;
    }

    __shared__ float4 l1[4][64];
    __shared__ float4 l2[4][64];
    l1[cl][lane].x = s1x; l1[cl][lane].y = s1y; l1[cl][lane].z = s1z; l1[cl][lane].w = s1w;
    l2[cl][lane].x = s2x; l2[cl][lane].y = s2y; l2[cl][lane].z = s2z; l2[cl][lane].w = s2w;
    __syncthreads();

    if (tid < 128) {
        const int t = tid & 63;
        const float4* src = (tid < 64) ? &l1[0][0] : &l2[0][0];
        const float4 a = src[t], c = src[64 + t], d = src[128 + t], e = src[192 + t];
        float4 r;
        r.x = (a.x + c.x) + (d.x + e.x);
        r.y = (a.y + c.y) + (d.y + e.y);
        r.z = (a.z + c.z) + (d.z + e.z);
        r.w = (a.w + c.w) + (d.w + e.w);
        float* dst = (tid < 64) ? part1 : part2;
        *(float4*)(dst + ((size_t)chunk * Bv + b) * Pv + ps * 256 + (t << 2)) = r;
    }
}

// ---------------------------------------------------------------------------
// Phase 2 (R4-proven): one block per batch, 1024 threads (1 pixel each).
// Reduce the 16 chunk partials (4 MB, L2/L3-hot), 3x3 zero-padded box sum via
// haloed LDS tile, cosine sim, mask, shuffle-based softmax (4 barriers).
// ---------------------------------------------------------------------------
__global__ __launch_bounds__(1024) void lss_final(
    const float* __restrict__ part1,
    const float* __restrict__ part2,
    const int*   __restrict__ mask,
    float*       __restrict__ out)
{
    const int b   = blockIdx.x;
    const int tid = threadIdx.x;           // p in [0, 1024)
    const int yy  = tid >> 5;
    const int xx  = tid & 31;
    const int wid = tid >> 6;              // 16 waves

    __shared__ float cs[(Hv + 2) * (Wv + 2)];
    __shared__ float wred[16];

    float s1 = 0.f, s2 = 0.f;
    #pragma unroll
    for (int ch = 0; ch < NCH; ++ch) {
        const size_t o = ((size_t)ch * Bv + b) * Pv + tid;
        s1 += part1[o];
        s2 += part2[o];
    }
    const float csum = s1;
    const float nx   = sqrtf(s2);

    for (int i = tid; i < (Hv + 2) * (Wv + 2); i += Pv) cs[i] = 0.f;
    __syncthreads();
    cs[(yy + 1) * (Wv + 2) + (xx + 1)] = csum;
    __syncthreads();

    float lm = 0.f;
    #pragma unroll
    for (int dy = 0; dy < 3; ++dy)
        #pragma unroll
        for (int dx = 0; dx < 3; ++dx)
            lm += cs[(yy + dy) * (Wv + 2) + (xx + dx)];
    lm *= (1.0f / 9.0f);

    // cosine sim: dot = lm*csum ; ny = sqrt(256)*|lm| = 16*|lm|
    const float ny  = 16.0f * fabsf(lm);
    const float sim = (lm * csum) / (fmaxf(nx, 1e-6f) * fmaxf(ny, 1e-6f));

    const float score = mask[b * Pv + tid] ? -INFINITY : -sim;

    // max reduce: wave shuffle + 16-entry LDS combine
    float v = score;
    #pragma unroll
    for (int off = 32; off > 0; off >>= 1)
        v = fmaxf(v, __shfl_xor(v, off, 64));
    if ((tid & 63) == 0) wred[wid] = v;
    __syncthreads();
    float m = wred[0];
    #pragma unroll
    for (int i = 1; i < 16; ++i) m = fmaxf(m, wred[i]);
    __syncthreads();

    const float e = expf(score - m);       // masked lanes -> 0

    // sum reduce
    v = e;
    #pragma unroll
    for (int off = 32; off > 0; off >>= 1)
        v += __shfl_xor(v, off, 64);
    if ((tid & 63) == 0) wred[wid] = v;
    __syncthreads();
    float denom = 0.f;
    #pragma unroll
    for (int i = 0; i < 16; ++i) denom += wred[i];

    out[b * Pv + tid] = e / denom;
}

extern "C" void kernel_launch(void* const* d_in, const int* in_sizes, int n_in,
                              void* d_out, int out_size, void* d_ws, size_t ws_size,
                              hipStream_t stream) {
    const float* x    = (const float*)d_in[0];
    const int*   mask = (const int*)d_in[1];
    float*       out  = (float*)d_out;

    float* part1 = (float*)d_ws;                      // NCH*B*P floats = 2 MB
    float* part2 = part1 + (size_t)NCH * Bv * Pv;     // 2 MB

    dim3 g1(NCH * PSPLIT, Bv);
    lss_phase1<<<g1, 256, 0, stream>>>(x, part1, part2);
    lss_final<<<Bv, Pv, 0, stream>>>(part1, part2, mask, out);
}